// Round 7
// baseline (793.359 us; speedup 1.0000x reference)
//
#include <hip/hip_runtime.h>
#include <cstddef>

#define NN 50000
#define EE 800000
#define NB 196  // ceil(50000/256)

typedef __attribute__((ext_vector_type(8))) _Float16 f16x8;
typedef __attribute__((ext_vector_type(4))) _Float16 f16x4;
typedef __attribute__((ext_vector_type(2))) _Float16 f16x2;
typedef __attribute__((ext_vector_type(4))) float f32x4;

// pack two fp32 -> packed fp16x2 (single v_cvt_pkrtz_f16_f32)
__device__ __forceinline__ unsigned pk2h(float a, float b) {
  auto h = __builtin_amdgcn_cvt_pkrtz(a, b);  // __fp16 ext_vector(2)
  return __builtin_bit_cast(unsigned, h);
}

// ============ CSR build ============
__global__ void k_zero_off(int* __restrict__ off) {
  int i = blockIdx.x * 256 + threadIdx.x;
  if (i <= NN) off[i] = 0;
}

__global__ void k_count(const int* __restrict__ src, const int* __restrict__ dst,
                        int* __restrict__ off) {
  int e = blockIdx.x * 256 + threadIdx.x;
  if (e < EE) {
    int s = src[e], d = dst[e];
    if (s >= 0 && s < NN && d >= 0 && d < NN) atomicAdd(&off[d], 1);
  }
}

__global__ void k_scanA(int* __restrict__ off, int* __restrict__ bsum) {
  __shared__ int sh[256];
  int t = threadIdx.x;
  int idx = blockIdx.x * 256 + t;
  int v = (idx < NN) ? off[idx] : 0;
  sh[t] = v;
  __syncthreads();
  for (int d = 1; d < 256; d <<= 1) {
    int x = (t >= d) ? sh[t - d] : 0;
    __syncthreads();
    sh[t] += x;
    __syncthreads();
  }
  if (idx < NN) off[idx] = sh[t] - v;
  if (t == 255) bsum[blockIdx.x] = sh[255];
}

__global__ void k_scanB(int* __restrict__ bsum, int* __restrict__ bpre,
                        int* __restrict__ off) {
  __shared__ int sh[256];
  int t = threadIdx.x;
  int v = (t < NB) ? bsum[t] : 0;
  sh[t] = v;
  __syncthreads();
  for (int d = 1; d < 256; d <<= 1) {
    int x = (t >= d) ? sh[t - d] : 0;
    __syncthreads();
    sh[t] += x;
    __syncthreads();
  }
  if (t < NB) bpre[t] = sh[t] - v;
  if (t == 255) off[NN] = sh[255];
}

__global__ void k_scanC(int* __restrict__ off, const int* __restrict__ bpre,
                        int* __restrict__ cursor) {
  int idx = blockIdx.x * 256 + threadIdx.x;
  if (idx < NN) {
    int o = off[idx] + bpre[blockIdx.x];
    off[idx] = o;
    cursor[idx] = o;
  }
}

__global__ void k_fill(const int* __restrict__ src, const int* __restrict__ dst,
                       const float* __restrict__ ew, int* __restrict__ cursor,
                       int* __restrict__ csrc, float* __restrict__ cew) {
  int e = blockIdx.x * 256 + threadIdx.x;
  if (e < EE) {
    int s = src[e], d = dst[e];
    if (s >= 0 && s < NN && d >= 0 && d < NN) {
      int p = atomicAdd(&cursor[d], 1);
      csrc[p] = s;
      cew[p] = ew[e];
    }
  }
}

__global__ void k_degdis(const int* __restrict__ off, const float* __restrict__ cew,
                         float* __restrict__ dis) {
  int i = blockIdx.x * 256 + threadIdx.x;
  if (i >= NN) return;
  int e0 = off[i], e1 = off[i + 1];
  float s = 1.0f;
  for (int e = e0; e < e1; ++e) s += cew[e];
  dis[i] = rsqrtf(s);
}

__global__ void k_affine(const float* __restrict__ g1, const float* __restrict__ be1,
                         const float* __restrict__ m1, const float* __restrict__ v1,
                         const float* __restrict__ g2, const float* __restrict__ be2,
                         const float* __restrict__ m2, const float* __restrict__ v2,
                         float* __restrict__ s1, float* __restrict__ u1,
                         float* __restrict__ s2, float* __restrict__ u2) {
  int f = threadIdx.x;
  float a1 = g1[f] * rsqrtf(v1[f] + 1e-5f);
  s1[f] = a1; u1[f] = be1[f] - m1[f] * a1;
  float a2 = g2[f] * rsqrtf(v2[f] + 1e-5f);
  s2[f] = a2; u2[f] = be2[f] - m2[f] * a2;
}

// ============ weight transpose+convert: WT[n][k] = fp16(W[k][n]) ============
__global__ void k_wt(const float* __restrict__ W, _Float16* __restrict__ WT,
                     int K, int N) {
  int k = blockIdx.x * 256 + threadIdx.x;
  int n = blockIdx.y;
  if (k < K) WT[(size_t)n * K + k] = (_Float16)W[(size_t)k * N + n];
}

// ============ x-stationary barrier-free MFMA GEMM ============
// C[M,NOUT](fp16) = A[M,K] @ BT[NOUT,K]^T.
// Each wave owns 16 rows x FULL NOUT cols. A panel (16 x K) lives entirely in
// registers (loaded once, fp32->fp16 inline for A32) -> A fetched from HBM
// exactly once chip-wide. B streams from L2 (<=384 KB, L2-resident) via a
// DEPTH-slot register pipeline. No LDS, no barriers.
template <int A32, int K, int NOUT, int MINW, int DEPTH>
__global__ __launch_bounds__(256, MINW) void k_gemm(const void* __restrict__ Ain,
                                                    const _Float16* __restrict__ BT,
                                                    _Float16* __restrict__ C,
                                                    int M) {
  constexpr int T = K / 32;        // K-steps
  constexpr int NG = NOUT / 64;    // B-groups per K-step (4 frags each)
  constexpr int G = T * NG;        // total groups
  constexpr int NC = NOUT / 16;    // col-groups (acc tiles)

  const int tid = threadIdx.x;
  const int lane = tid & 63;
  const int wid = tid >> 6;
  const int quad = lane >> 4;
  const int l16 = lane & 15;
  const int wrow = blockIdx.x * 64 + wid * 16;  // wave's first row
  const int arow = wrow + l16;
  const int arc = (arow < M) ? arow : 0;        // clamped (stores guarded)

  // ---- phase 1: A panel -> registers (read-once) ----
  f16x8 aK[T];
  if (A32) {
    const float* ap = (const float*)Ain + (size_t)arc * K + (quad << 3);
#pragma unroll
    for (int t = 0; t < T; ++t) {
      float4 u = *(const float4*)(ap + t * 32);
      float4 v = *(const float4*)(ap + t * 32 + 4);
      aK[t] = __builtin_bit_cast(f16x8,
          make_uint4(pk2h(u.x, u.y), pk2h(u.z, u.w), pk2h(v.x, v.y), pk2h(v.z, v.w)));
    }
  } else {
    const _Float16* ap = (const _Float16*)Ain + (size_t)arc * K + (quad << 3);
#pragma unroll
    for (int t = 0; t < T; ++t) aK[t] = *(const f16x8*)(ap + t * 32);
  }

  // ---- phase 2: stream B from L2, MFMA ----
  const _Float16* bbase = BT + (size_t)l16 * K + (quad << 3);
  f32x4 acc[NC];
#pragma unroll
  for (int c = 0; c < NC; ++c) acc[c] = (f32x4){0.f, 0.f, 0.f, 0.f};
  f16x8 bs[DEPTH][4];

#define LOADB(g)                                                              \
  do {                                                                        \
    int t_ = (g) / NG, p_ = (g) % NG;                                         \
    _Pragma("unroll") for (int j = 0; j < 4; ++j)                             \
        bs[(g) % DEPTH][j] =                                                  \
            *(const f16x8*)(bbase + (size_t)((p_ * 4 + j) * 16) * K + t_ * 32); \
  } while (0)

#define DOMF(g)                                                               \
  do {                                                                        \
    int t_ = (g) / NG, p_ = (g) % NG;                                         \
    _Pragma("unroll") for (int j = 0; j < 4; ++j)                             \
        acc[p_ * 4 + j] = __builtin_amdgcn_mfma_f32_16x16x32_f16(             \
            aK[t_], bs[(g) % DEPTH][j], acc[p_ * 4 + j], 0, 0, 0);            \
  } while (0)

#pragma unroll
  for (int g = 0; g < DEPTH - 1 && g < G; ++g) LOADB(g);
#pragma unroll
  for (int g = 0; g < G; ++g) {
    if (g + DEPTH - 1 < G) LOADB(g + DEPTH - 1);
    DOMF(g);
  }
#undef LOADB
#undef DOMF

  // ---- epilogue: C/D layout col=lane&15, row=quad*4+reg ----
  const int rb = wrow + (quad << 2);
#pragma unroll
  for (int c = 0; c < NC; ++c) {
#pragma unroll
    for (int r = 0; r < 4; ++r) {
      int row = rb + r;
      if (row < M) C[(size_t)row * NOUT + c * 16 + l16] = (_Float16)acc[c][r];
    }
  }
}

// ============ CSR aggregation (F=256, fp16 rows) + fused BN affine + ReLU -> fp16 out ============
__global__ __launch_bounds__(256) void k_agg256(const _Float16* __restrict__ hW,
                                                const float* __restrict__ dis,
                                                const float* __restrict__ b,
                                                const int* __restrict__ off,
                                                const int* __restrict__ csrc,
                                                const float* __restrict__ cew,
                                                const float* __restrict__ s,
                                                const float* __restrict__ u,
                                                _Float16* __restrict__ hout) {
  int i = (blockIdx.x << 2) + (threadIdx.x >> 6);
  if (i >= NN) return;
  int lane = threadIdx.x & 63;
  float di = dis[i];
  float4 bb = *(const float4*)(b + (lane << 2));
  f16x4 hv = *(const f16x4*)(hW + (size_t)i * 256 + (lane << 2));
  float d2 = di * di;
  float4 acc;
  acc.x = fmaf((float)hv.x, d2, bb.x);
  acc.y = fmaf((float)hv.y, d2, bb.y);
  acc.z = fmaf((float)hv.z, d2, bb.z);
  acc.w = fmaf((float)hv.w, d2, bb.w);
  int e0 = off[i], e1 = off[i + 1];
  int e = e0;
  for (; e + 3 < e1; e += 4) {
    int sa = csrc[e], sb = csrc[e + 1], sc = csrc[e + 2], sd = csrc[e + 3];
    float wa = dis[sa] * cew[e] * di;
    float wb = dis[sb] * cew[e + 1] * di;
    float wc = dis[sc] * cew[e + 2] * di;
    float wd = dis[sd] * cew[e + 3] * di;
    f16x4 ra = *(const f16x4*)(hW + (size_t)sa * 256 + (lane << 2));
    f16x4 rb = *(const f16x4*)(hW + (size_t)sb * 256 + (lane << 2));
    f16x4 rc = *(const f16x4*)(hW + (size_t)sc * 256 + (lane << 2));
    f16x4 rd = *(const f16x4*)(hW + (size_t)sd * 256 + (lane << 2));
    acc.x = fmaf((float)ra.x, wa, acc.x); acc.y = fmaf((float)ra.y, wa, acc.y);
    acc.z = fmaf((float)ra.z, wa, acc.z); acc.w = fmaf((float)ra.w, wa, acc.w);
    acc.x = fmaf((float)rb.x, wb, acc.x); acc.y = fmaf((float)rb.y, wb, acc.y);
    acc.z = fmaf((float)rb.z, wb, acc.z); acc.w = fmaf((float)rb.w, wb, acc.w);
    acc.x = fmaf((float)rc.x, wc, acc.x); acc.y = fmaf((float)rc.y, wc, acc.y);
    acc.z = fmaf((float)rc.z, wc, acc.z); acc.w = fmaf((float)rc.w, wc, acc.w);
    acc.x = fmaf((float)rd.x, wd, acc.x); acc.y = fmaf((float)rd.y, wd, acc.y);
    acc.z = fmaf((float)rd.z, wd, acc.z); acc.w = fmaf((float)rd.w, wd, acc.w);
  }
  for (; e < e1; ++e) {
    int sa = csrc[e];
    float wa = dis[sa] * cew[e] * di;
    f16x4 ra = *(const f16x4*)(hW + (size_t)sa * 256 + (lane << 2));
    acc.x = fmaf((float)ra.x, wa, acc.x); acc.y = fmaf((float)ra.y, wa, acc.y);
    acc.z = fmaf((float)ra.z, wa, acc.z); acc.w = fmaf((float)ra.w, wa, acc.w);
  }
  // BN affine + ReLU + fp16 pack
  float4 sv = *(const float4*)(s + (lane << 2));
  float4 uv = *(const float4*)(u + (lane << 2));
  float r0 = fmaxf(fmaf(acc.x, sv.x, uv.x), 0.f);
  float r1 = fmaxf(fmaf(acc.y, sv.y, uv.y), 0.f);
  float r2 = fmaxf(fmaf(acc.z, sv.z, uv.z), 0.f);
  float r3 = fmaxf(fmaf(acc.w, sv.w, uv.w), 0.f);
  uint2 pk;
  pk.x = pk2h(r0, r1);
  pk.y = pk2h(r2, r3);
  *(uint2*)&hout[(size_t)i * 256 + (lane << 2)] = pk;
}

// ============ layer-3 aggregation (F=128, fp16 rows) + fused L2 norm -> d_out (fp32) ============
__global__ __launch_bounds__(256) void k_agg128_l2(const _Float16* __restrict__ hW,
                                                   const float* __restrict__ dis,
                                                   const float* __restrict__ b,
                                                   const int* __restrict__ off,
                                                   const int* __restrict__ csrc,
                                                   const float* __restrict__ cew,
                                                   float* __restrict__ out) {
  int i = (blockIdx.x << 2) + (threadIdx.x >> 6);
  if (i >= NN) return;
  int lane = threadIdx.x & 63;
  float di = dis[i];
  float2 bb = *(const float2*)(b + (lane << 1));
  f16x2 hv = *(const f16x2*)(hW + (size_t)i * 128 + (lane << 1));
  float d2 = di * di;
  float2 acc;
  acc.x = fmaf((float)hv.x, d2, bb.x);
  acc.y = fmaf((float)hv.y, d2, bb.y);
  int e0 = off[i], e1 = off[i + 1];
  int e = e0;
  for (; e + 3 < e1; e += 4) {
    int sa = csrc[e], sb = csrc[e + 1], sc = csrc[e + 2], sd = csrc[e + 3];
    float wa = dis[sa] * cew[e] * di;
    float wb = dis[sb] * cew[e + 1] * di;
    float wc = dis[sc] * cew[e + 2] * di;
    float wd = dis[sd] * cew[e + 3] * di;
    f16x2 ra = *(const f16x2*)(hW + (size_t)sa * 128 + (lane << 1));
    f16x2 rb = *(const f16x2*)(hW + (size_t)sb * 128 + (lane << 1));
    f16x2 rc = *(const f16x2*)(hW + (size_t)sc * 128 + (lane << 1));
    f16x2 rd = *(const f16x2*)(hW + (size_t)sd * 128 + (lane << 1));
    acc.x = fmaf((float)ra.x, wa, acc.x); acc.y = fmaf((float)ra.y, wa, acc.y);
    acc.x = fmaf((float)rb.x, wb, acc.x); acc.y = fmaf((float)rb.y, wb, acc.y);
    acc.x = fmaf((float)rc.x, wc, acc.x); acc.y = fmaf((float)rc.y, wc, acc.y);
    acc.x = fmaf((float)rd.x, wd, acc.x); acc.y = fmaf((float)rd.y, wd, acc.y);
  }
  for (; e < e1; ++e) {
    int sa = csrc[e];
    float wa = dis[sa] * cew[e] * di;
    f16x2 ra = *(const f16x2*)(hW + (size_t)sa * 128 + (lane << 1));
    acc.x = fmaf((float)ra.x, wa, acc.x); acc.y = fmaf((float)ra.y, wa, acc.y);
  }
  float ss = fmaf(acc.x, acc.x, acc.y * acc.y);
#pragma unroll
  for (int o = 32; o > 0; o >>= 1) ss += __shfl_xor(ss, o, 64);
  float sc2 = 1.0f / fmaxf(sqrtf(ss), 1e-12f);
  acc.x *= sc2;
  acc.y *= sc2;
  *(float2*)(out + (size_t)i * 128 + (lane << 1)) = acc;
}

extern "C" void kernel_launch(void* const* d_in, const int* in_sizes, int n_in,
                              void* d_out, int out_size, void* d_ws, size_t ws_size,
                              hipStream_t stream) {
  // ws layout (4-byte units):
  const size_t OFF_CUR = 50176, OFF_BS = 100352, OFF_BP = 100608;
  const size_t OFF_CS = 100864, OFF_CW = 900864, OFF_DIS = 1700864;
  const size_t OFF_AFF = 1751040, OFF_HW = 1752064;
  const size_t OFF_HB = OFF_HW + (size_t)NN * 256;        // fp16 h: NN*256 halfs fits in NN*128 units
  const size_t OFF_WT1 = OFF_HB + (size_t)NN * 128;
  const size_t OFF_WT2 = OFF_WT1 + 768 * 256 / 2;
  const size_t OFF_WT3 = OFF_WT2 + 256 * 256 / 2;
  const size_t WS_UNITS = OFF_WT3 + 256 * 128 / 2 + 256;
  if (ws_size < WS_UNITS * 4) return;  // fail cleanly, never OOB

  const float* x  = (const float*)d_in[0];
  const int* ei   = (const int*)d_in[1];
  const float* ew = (const float*)d_in[2];
  const float* W1 = (const float*)d_in[3];
  const float* b1 = (const float*)d_in[4];
  const float* W2 = (const float*)d_in[5];
  const float* b2 = (const float*)d_in[6];
  const float* W3 = (const float*)d_in[7];
  const float* b3 = (const float*)d_in[8];
  const float* g1 = (const float*)d_in[9];
  const float* be1 = (const float*)d_in[10];
  const float* m1 = (const float*)d_in[11];
  const float* v1 = (const float*)d_in[12];
  const float* g2 = (const float*)d_in[13];
  const float* be2 = (const float*)d_in[14];
  const float* m2 = (const float*)d_in[15];
  const float* v2 = (const float*)d_in[16];
  float* out = (float*)d_out;
  const int* src = ei;
  const int* dstp = ei + EE;

  int* wsi = (int*)d_ws;
  float* wsf = (float*)d_ws;
  int* off = wsi;
  int* cursor = wsi + OFF_CUR;
  int* bsum = wsi + OFF_BS;
  int* bpre = wsi + OFF_BP;
  int* csrc = wsi + OFF_CS;
  float* cew = wsf + OFF_CW;
  float* dis = wsf + OFF_DIS;
  float* s1 = wsf + OFF_AFF;
  float* u1 = s1 + 256;
  float* s2 = u1 + 256;
  float* u2 = s2 + 256;
  _Float16* hW = (_Float16*)(wsf + OFF_HW);
  _Float16* hb = (_Float16*)(wsi + OFF_HB);
  _Float16* wT1 = (_Float16*)(wsi + OFF_WT1);
  _Float16* wT2 = (_Float16*)(wsi + OFF_WT2);
  _Float16* wT3 = (_Float16*)(wsi + OFF_WT3);

  dim3 b256(256);
  const int EB = (EE + 255) / 256;
  // CSR build + norm precompute
  k_zero_off<<<NB, b256, 0, stream>>>(off);
  k_count<<<EB, b256, 0, stream>>>(src, dstp, off);
  k_scanA<<<NB, b256, 0, stream>>>(off, bsum);
  k_scanB<<<1, b256, 0, stream>>>(bsum, bpre, off);
  k_scanC<<<NB, b256, 0, stream>>>(off, bpre, cursor);
  k_fill<<<EB, b256, 0, stream>>>(src, dstp, ew, cursor, csrc, cew);
  k_degdis<<<NB, b256, 0, stream>>>(off, cew, dis);
  k_affine<<<1, b256, 0, stream>>>(g1, be1, m1, v1, g2, be2, m2, v2, s1, u1, s2, u2);
  // weight transpose+convert
  k_wt<<<dim3(3, 256), b256, 0, stream>>>(W1, wT1, 768, 256);
  k_wt<<<dim3(1, 256), b256, 0, stream>>>(W2, wT2, 256, 256);
  k_wt<<<dim3(1, 128), b256, 0, stream>>>(W3, wT3, 256, 128);

  const int GB = (NN + 63) / 64;  // 782 blocks (4 waves x 16 rows each)
  const int AGB = (NN + 3) / 4;
  // Layer 1: x (fp32, inline-converted) @ W1
  k_gemm<1, 768, 256, 2, 2><<<GB, b256, 0, stream>>>(x, wT1, hW, NN);
  k_agg256<<<AGB, b256, 0, stream>>>(hW, dis, b1, off, csrc, cew, s1, u1, hb);
  // Layer 2: hb (fp16) @ W2
  k_gemm<0, 256, 256, 2, 3><<<GB, b256, 0, stream>>>(hb, wT2, hW, NN);
  k_agg256<<<AGB, b256, 0, stream>>>(hW, dis, b2, off, csrc, cew, s2, u2, hb);
  // Layer 3: hb @ W3, then aggregate + L2 norm -> d_out
  k_gemm<0, 256, 128, 3, 3><<<GB, b256, 0, stream>>>(hb, wT3, hW, NN);
  k_agg128_l2<<<AGB, b256, 0, stream>>>(hW, dis, b3, off, csrc, cew, out);
}

// Round 8
// 582.296 us; speedup vs baseline: 1.3625x; 1.3625x over previous
//
#include <hip/hip_runtime.h>
#include <cstddef>

#define NN 50000
#define EE 800000
#define NB 196  // ceil(50000/256)

typedef __attribute__((ext_vector_type(8))) _Float16 f16x8;
typedef __attribute__((ext_vector_type(4))) _Float16 f16x4;
typedef __attribute__((ext_vector_type(2))) _Float16 f16x2;
typedef __attribute__((ext_vector_type(4))) float f32x4;

// pack two fp32 -> packed fp16x2 (single v_cvt_pkrtz_f16_f32)
__device__ __forceinline__ unsigned pk2h(float a, float b) {
  auto h = __builtin_amdgcn_cvt_pkrtz(a, b);  // __fp16 ext_vector(2)
  return __builtin_bit_cast(unsigned, h);
}

// ============ CSR build ============
__global__ void k_zero_off(int* __restrict__ off) {
  int i = blockIdx.x * 256 + threadIdx.x;
  if (i <= NN) off[i] = 0;
}

__global__ void k_count(const int* __restrict__ src, const int* __restrict__ dst,
                        int* __restrict__ off) {
  int e = blockIdx.x * 256 + threadIdx.x;
  if (e < EE) {
    int s = src[e], d = dst[e];
    if (s >= 0 && s < NN && d >= 0 && d < NN) atomicAdd(&off[d], 1);
  }
}

__global__ void k_scanA(int* __restrict__ off, int* __restrict__ bsum) {
  __shared__ int sh[256];
  int t = threadIdx.x;
  int idx = blockIdx.x * 256 + t;
  int v = (idx < NN) ? off[idx] : 0;
  sh[t] = v;
  __syncthreads();
  for (int d = 1; d < 256; d <<= 1) {
    int x = (t >= d) ? sh[t - d] : 0;
    __syncthreads();
    sh[t] += x;
    __syncthreads();
  }
  if (idx < NN) off[idx] = sh[t] - v;
  if (t == 255) bsum[blockIdx.x] = sh[255];
}

__global__ void k_scanB(int* __restrict__ bsum, int* __restrict__ bpre,
                        int* __restrict__ off) {
  __shared__ int sh[256];
  int t = threadIdx.x;
  int v = (t < NB) ? bsum[t] : 0;
  sh[t] = v;
  __syncthreads();
  for (int d = 1; d < 256; d <<= 1) {
    int x = (t >= d) ? sh[t - d] : 0;
    __syncthreads();
    sh[t] += x;
    __syncthreads();
  }
  if (t < NB) bpre[t] = sh[t] - v;
  if (t == 255) off[NN] = sh[255];
}

__global__ void k_scanC(int* __restrict__ off, const int* __restrict__ bpre,
                        int* __restrict__ cursor) {
  int idx = blockIdx.x * 256 + threadIdx.x;
  if (idx < NN) {
    int o = off[idx] + bpre[blockIdx.x];
    off[idx] = o;
    cursor[idx] = o;
  }
}

__global__ void k_fill(const int* __restrict__ src, const int* __restrict__ dst,
                       const float* __restrict__ ew, int* __restrict__ cursor,
                       int* __restrict__ csrc, float* __restrict__ cew) {
  int e = blockIdx.x * 256 + threadIdx.x;
  if (e < EE) {
    int s = src[e], d = dst[e];
    if (s >= 0 && s < NN && d >= 0 && d < NN) {
      int p = atomicAdd(&cursor[d], 1);
      csrc[p] = s;
      cew[p] = ew[e];
    }
  }
}

__global__ void k_degdis(const int* __restrict__ off, const float* __restrict__ cew,
                         float* __restrict__ dis) {
  int i = blockIdx.x * 256 + threadIdx.x;
  if (i >= NN) return;
  int e0 = off[i], e1 = off[i + 1];
  float s = 1.0f;
  for (int e = e0; e < e1; ++e) s += cew[e];
  dis[i] = rsqrtf(s);
}

__global__ void k_affine(const float* __restrict__ g1, const float* __restrict__ be1,
                         const float* __restrict__ m1, const float* __restrict__ v1,
                         const float* __restrict__ g2, const float* __restrict__ be2,
                         const float* __restrict__ m2, const float* __restrict__ v2,
                         float* __restrict__ s1, float* __restrict__ u1,
                         float* __restrict__ s2, float* __restrict__ u2) {
  int f = threadIdx.x;
  float a1 = g1[f] * rsqrtf(v1[f] + 1e-5f);
  s1[f] = a1; u1[f] = be1[f] - m1[f] * a1;
  float a2 = g2[f] * rsqrtf(v2[f] + 1e-5f);
  s2[f] = a2; u2[f] = be2[f] - m2[f] * a2;
}

// ============ weight transpose+convert: WT[n][k] = fp16(W[k][n]) ============
__global__ void k_wt(const float* __restrict__ W, _Float16* __restrict__ WT,
                     int K, int N) {
  int k = blockIdx.x * 256 + threadIdx.x;
  int n = blockIdx.y;
  if (k < K) WT[(size_t)n * K + k] = (_Float16)W[(size_t)k * N + n];
}

// ============ fp16 MFMA GEMM: C[M,Nout](fp16) = A[M,K] @ BT[Nout,K]^T ============
// 64x128 tile, BK=64, 4 waves (2x2), each wave 32x64 via 2x4 grid of 16x16x32 MFMA
// (x2 K-substeps). Register prefetch of next BK-tile; 2 barriers per 64-K-step
// (half the barrier count of the BK=32 version).
// A32: A is fp32 (converted to fp16 at LDS-commit); else A is fp16.
#define LDA 72  // LDS row stride in halfs (64 + 8 pad): 144B rows, ~2-way max aliasing
template <int A32>
__global__ __launch_bounds__(256) void k_gemm(const void* __restrict__ Ain,
                                              const _Float16* __restrict__ BT,
                                              _Float16* __restrict__ C,
                                              int M, int K, int Nout) {
  __shared__ _Float16 As[64 * LDA];
  __shared__ _Float16 Bs[128 * LDA];
  const int tid = threadIdx.x;
  const int bm = blockIdx.y << 6;
  const int bn = blockIdx.x << 7;
  const int lane = tid & 63;
  const int wid = tid >> 6;
  const int wm = (wid & 1) << 5;   // 0 / 32
  const int wn = (wid >> 1) << 6;  // 0 / 64
  const int quad = lane >> 4;
  const int l16 = lane & 15;

  // staging: 16B chunks of 8 halfs. A tile 64x64 halfs = 512 chunks (2/thread);
  // B tile 128x64 = 1024 chunks (4/thread). kc fixed per thread.
  const int srow = tid >> 3, skc = tid & 7;  // srow in [0,32), skc in [0,8)
  const int agr0 = bm + srow, agr1 = bm + srow + 32;
  const int aok0 = (agr0 < M), aok1 = (agr1 < M);
  const float* ap32_0 = (const float*)Ain + (size_t)agr0 * K + (skc << 3);
  const float* ap32_1 = (const float*)Ain + (size_t)agr1 * K + (skc << 3);
  const _Float16* ap16_0 = (const _Float16*)Ain + (size_t)agr0 * K + (skc << 3);
  const _Float16* ap16_1 = (const _Float16*)Ain + (size_t)agr1 * K + (skc << 3);
  const _Float16* bp0 = BT + (size_t)(bn + srow) * K + (skc << 3);
  const _Float16* bp1 = BT + (size_t)(bn + 32 + srow) * K + (skc << 3);
  const _Float16* bp2 = BT + (size_t)(bn + 64 + srow) * K + (skc << 3);
  const _Float16* bp3 = BT + (size_t)(bn + 96 + srow) * K + (skc << 3);

  f32x4 acc[2][4] = {};

  uint4 ra0, ra1;
  float4 ra0lo, ra0hi, ra1lo, ra1hi;
  uint4 rb0, rb1, rb2, rb3;

#define ISSUE(k0)                                                             \
  do {                                                                        \
    if (A32) {                                                                \
      if (aok0) {                                                             \
        ra0lo = *(const float4*)(ap32_0 + (k0));                              \
        ra0hi = *(const float4*)(ap32_0 + (k0) + 4);                          \
      } else {                                                                \
        ra0lo = make_float4(0.f, 0.f, 0.f, 0.f);                              \
        ra0hi = make_float4(0.f, 0.f, 0.f, 0.f);                              \
      }                                                                       \
      if (aok1) {                                                             \
        ra1lo = *(const float4*)(ap32_1 + (k0));                              \
        ra1hi = *(const float4*)(ap32_1 + (k0) + 4);                          \
      } else {                                                                \
        ra1lo = make_float4(0.f, 0.f, 0.f, 0.f);                              \
        ra1hi = make_float4(0.f, 0.f, 0.f, 0.f);                              \
      }                                                                       \
    } else {                                                                  \
      ra0 = aok0 ? *(const uint4*)(ap16_0 + (k0)) : make_uint4(0, 0, 0, 0);   \
      ra1 = aok1 ? *(const uint4*)(ap16_1 + (k0)) : make_uint4(0, 0, 0, 0);   \
    }                                                                         \
    rb0 = *(const uint4*)(bp0 + (k0));                                        \
    rb1 = *(const uint4*)(bp1 + (k0));                                        \
    rb2 = *(const uint4*)(bp2 + (k0));                                        \
    rb3 = *(const uint4*)(bp3 + (k0));                                        \
  } while (0)

#define COMMIT()                                                              \
  do {                                                                        \
    uint4 va0, va1;                                                           \
    if (A32) {                                                                \
      va0.x = pk2h(ra0lo.x, ra0lo.y); va0.y = pk2h(ra0lo.z, ra0lo.w);         \
      va0.z = pk2h(ra0hi.x, ra0hi.y); va0.w = pk2h(ra0hi.z, ra0hi.w);         \
      va1.x = pk2h(ra1lo.x, ra1lo.y); va1.y = pk2h(ra1lo.z, ra1lo.w);         \
      va1.z = pk2h(ra1hi.x, ra1hi.y); va1.w = pk2h(ra1hi.z, ra1hi.w);         \
    } else {                                                                  \
      va0 = ra0; va1 = ra1;                                                   \
    }                                                                         \
    *(uint4*)&As[srow * LDA + (skc << 3)] = va0;                              \
    *(uint4*)&As[(srow + 32) * LDA + (skc << 3)] = va1;                       \
    *(uint4*)&Bs[srow * LDA + (skc << 3)] = rb0;                              \
    *(uint4*)&Bs[(srow + 32) * LDA + (skc << 3)] = rb1;                       \
    *(uint4*)&Bs[(srow + 64) * LDA + (skc << 3)] = rb2;                       \
    *(uint4*)&Bs[(srow + 96) * LDA + (skc << 3)] = rb3;                       \
  } while (0)

#define COMPUTE()                                                             \
  do {                                                                        \
    _Pragma("unroll") for (int s = 0; s < 2; ++s) {                           \
      f16x8 af[2], bfr[4];                                                    \
      _Pragma("unroll") for (int mt = 0; mt < 2; ++mt)                        \
          af[mt] = *(const f16x8*)&As[(wm + (mt << 4) + l16) * LDA + (s << 5) + (quad << 3)]; \
      _Pragma("unroll") for (int nt = 0; nt < 4; ++nt)                        \
          bfr[nt] = *(const f16x8*)&Bs[(wn + (nt << 4) + l16) * LDA + (s << 5) + (quad << 3)]; \
      _Pragma("unroll") for (int mt = 0; mt < 2; ++mt)                        \
          _Pragma("unroll") for (int nt = 0; nt < 4; ++nt)                    \
              acc[mt][nt] = __builtin_amdgcn_mfma_f32_16x16x32_f16(af[mt], bfr[nt], acc[mt][nt], 0, 0, 0); \
    }                                                                         \
  } while (0)

  const int T = K >> 6;  // 64-wide K-steps (12 / 4 / 4)

  ISSUE(0);
  COMMIT();
  __syncthreads();
  for (int t = 0; t < T; ++t) {
    if (t + 1 < T) ISSUE((t + 1) << 6);
    COMPUTE();
    __syncthreads();  // all waves done reading this tile
    if (t + 1 < T) {
      COMMIT();
      __syncthreads();  // new tile visible
    }
  }
#undef ISSUE
#undef COMMIT
#undef COMPUTE

  // ---- epilogue: C/D layout col=lane&15, row=quad*4+reg; store fp16 ----
  const int rbase = bm + wm + (quad << 2);
#pragma unroll
  for (int mt = 0; mt < 2; ++mt) {
#pragma unroll
    for (int reg = 0; reg < 4; ++reg) {
      int r = rbase + (mt << 4) + reg;
      if (r < M) {
        _Float16* crow = C + (size_t)r * Nout + bn + wn + l16;
#pragma unroll
        for (int nt = 0; nt < 4; ++nt) crow[nt << 4] = (_Float16)acc[mt][nt][reg];
      }
    }
  }
}

// ============ CSR aggregation (F=256, fp16 rows) + fused BN affine + ReLU -> fp16 out ============
__global__ __launch_bounds__(256) void k_agg256(const _Float16* __restrict__ hW,
                                                const float* __restrict__ dis,
                                                const float* __restrict__ b,
                                                const int* __restrict__ off,
                                                const int* __restrict__ csrc,
                                                const float* __restrict__ cew,
                                                const float* __restrict__ s,
                                                const float* __restrict__ u,
                                                _Float16* __restrict__ hout) {
  int i = (blockIdx.x << 2) + (threadIdx.x >> 6);
  if (i >= NN) return;
  int lane = threadIdx.x & 63;
  float di = dis[i];
  float4 bb = *(const float4*)(b + (lane << 2));
  f16x4 hv = *(const f16x4*)(hW + (size_t)i * 256 + (lane << 2));
  float d2 = di * di;
  float4 acc;
  acc.x = fmaf((float)hv.x, d2, bb.x);
  acc.y = fmaf((float)hv.y, d2, bb.y);
  acc.z = fmaf((float)hv.z, d2, bb.z);
  acc.w = fmaf((float)hv.w, d2, bb.w);
  int e0 = off[i], e1 = off[i + 1];
  int e = e0;
  for (; e + 3 < e1; e += 4) {
    int sa = csrc[e], sb = csrc[e + 1], sc = csrc[e + 2], sd = csrc[e + 3];
    float wa = dis[sa] * cew[e] * di;
    float wb = dis[sb] * cew[e + 1] * di;
    float wc = dis[sc] * cew[e + 2] * di;
    float wd = dis[sd] * cew[e + 3] * di;
    f16x4 ra = *(const f16x4*)(hW + (size_t)sa * 256 + (lane << 2));
    f16x4 rb = *(const f16x4*)(hW + (size_t)sb * 256 + (lane << 2));
    f16x4 rc = *(const f16x4*)(hW + (size_t)sc * 256 + (lane << 2));
    f16x4 rd = *(const f16x4*)(hW + (size_t)sd * 256 + (lane << 2));
    acc.x = fmaf((float)ra.x, wa, acc.x); acc.y = fmaf((float)ra.y, wa, acc.y);
    acc.z = fmaf((float)ra.z, wa, acc.z); acc.w = fmaf((float)ra.w, wa, acc.w);
    acc.x = fmaf((float)rb.x, wb, acc.x); acc.y = fmaf((float)rb.y, wb, acc.y);
    acc.z = fmaf((float)rb.z, wb, acc.z); acc.w = fmaf((float)rb.w, wb, acc.w);
    acc.x = fmaf((float)rc.x, wc, acc.x); acc.y = fmaf((float)rc.y, wc, acc.y);
    acc.z = fmaf((float)rc.z, wc, acc.z); acc.w = fmaf((float)rc.w, wc, acc.w);
    acc.x = fmaf((float)rd.x, wd, acc.x); acc.y = fmaf((float)rd.y, wd, acc.y);
    acc.z = fmaf((float)rd.z, wd, acc.z); acc.w = fmaf((float)rd.w, wd, acc.w);
  }
  for (; e < e1; ++e) {
    int sa = csrc[e];
    float wa = dis[sa] * cew[e] * di;
    f16x4 ra = *(const f16x4*)(hW + (size_t)sa * 256 + (lane << 2));
    acc.x = fmaf((float)ra.x, wa, acc.x); acc.y = fmaf((float)ra.y, wa, acc.y);
    acc.z = fmaf((float)ra.z, wa, acc.z); acc.w = fmaf((float)ra.w, wa, acc.w);
  }
  // BN affine + ReLU + fp16 pack
  float4 sv = *(const float4*)(s + (lane << 2));
  float4 uv = *(const float4*)(u + (lane << 2));
  float r0 = fmaxf(fmaf(acc.x, sv.x, uv.x), 0.f);
  float r1 = fmaxf(fmaf(acc.y, sv.y, uv.y), 0.f);
  float r2 = fmaxf(fmaf(acc.z, sv.z, uv.z), 0.f);
  float r3 = fmaxf(fmaf(acc.w, sv.w, uv.w), 0.f);
  uint2 pk;
  pk.x = pk2h(r0, r1);
  pk.y = pk2h(r2, r3);
  *(uint2*)&hout[(size_t)i * 256 + (lane << 2)] = pk;
}

// ============ layer-3 aggregation (F=128, fp16 rows) + fused L2 norm -> d_out (fp32) ============
__global__ __launch_bounds__(256) void k_agg128_l2(const _Float16* __restrict__ hW,
                                                   const float* __restrict__ dis,
                                                   const float* __restrict__ b,
                                                   const int* __restrict__ off,
                                                   const int* __restrict__ csrc,
                                                   const float* __restrict__ cew,
                                                   float* __restrict__ out) {
  int i = (blockIdx.x << 2) + (threadIdx.x >> 6);
  if (i >= NN) return;
  int lane = threadIdx.x & 63;
  float di = dis[i];
  float2 bb = *(const float2*)(b + (lane << 1));
  f16x2 hv = *(const f16x2*)(hW + (size_t)i * 128 + (lane << 1));
  float d2 = di * di;
  float2 acc;
  acc.x = fmaf((float)hv.x, d2, bb.x);
  acc.y = fmaf((float)hv.y, d2, bb.y);
  int e0 = off[i], e1 = off[i + 1];
  int e = e0;
  for (; e + 3 < e1; e += 4) {
    int sa = csrc[e], sb = csrc[e + 1], sc = csrc[e + 2], sd = csrc[e + 3];
    float wa = dis[sa] * cew[e] * di;
    float wb = dis[sb] * cew[e + 1] * di;
    float wc = dis[sc] * cew[e + 2] * di;
    float wd = dis[sd] * cew[e + 3] * di;
    f16x2 ra = *(const f16x2*)(hW + (size_t)sa * 128 + (lane << 1));
    f16x2 rb = *(const f16x2*)(hW + (size_t)sb * 128 + (lane << 1));
    f16x2 rc = *(const f16x2*)(hW + (size_t)sc * 128 + (lane << 1));
    f16x2 rd = *(const f16x2*)(hW + (size_t)sd * 128 + (lane << 1));
    acc.x = fmaf((float)ra.x, wa, acc.x); acc.y = fmaf((float)ra.y, wa, acc.y);
    acc.x = fmaf((float)rb.x, wb, acc.x); acc.y = fmaf((float)rb.y, wb, acc.y);
    acc.x = fmaf((float)rc.x, wc, acc.x); acc.y = fmaf((float)rc.y, wc, acc.y);
    acc.x = fmaf((float)rd.x, wd, acc.x); acc.y = fmaf((float)rd.y, wd, acc.y);
  }
  for (; e < e1; ++e) {
    int sa = csrc[e];
    float wa = dis[sa] * cew[e] * di;
    f16x2 ra = *(const f16x2*)(hW + (size_t)sa * 128 + (lane << 1));
    acc.x = fmaf((float)ra.x, wa, acc.x); acc.y = fmaf((float)ra.y, wa, acc.y);
  }
  float ss = fmaf(acc.x, acc.x, acc.y * acc.y);
#pragma unroll
  for (int o = 32; o > 0; o >>= 1) ss += __shfl_xor(ss, o, 64);
  float sc2 = 1.0f / fmaxf(sqrtf(ss), 1e-12f);
  acc.x *= sc2;
  acc.y *= sc2;
  *(float2*)(out + (size_t)i * 128 + (lane << 1)) = acc;
}

extern "C" void kernel_launch(void* const* d_in, const int* in_sizes, int n_in,
                              void* d_out, int out_size, void* d_ws, size_t ws_size,
                              hipStream_t stream) {
  // ws layout (4-byte units):
  const size_t OFF_CUR = 50176, OFF_BS = 100352, OFF_BP = 100608;
  const size_t OFF_CS = 100864, OFF_CW = 900864, OFF_DIS = 1700864;
  const size_t OFF_AFF = 1751040, OFF_HW = 1752064;
  const size_t OFF_HB = OFF_HW + (size_t)NN * 256;        // fp16 h: NN*256 halfs fits in NN*128 units
  const size_t OFF_WT1 = OFF_HB + (size_t)NN * 128;
  const size_t OFF_WT2 = OFF_WT1 + 768 * 256 / 2;
  const size_t OFF_WT3 = OFF_WT2 + 256 * 256 / 2;
  const size_t WS_UNITS = OFF_WT3 + 256 * 128 / 2 + 256;
  if (ws_size < WS_UNITS * 4) return;  // fail cleanly, never OOB

  const float* x  = (const float*)d_in[0];
  const int* ei   = (const int*)d_in[1];
  const float* ew = (const float*)d_in[2];
  const float* W1 = (const float*)d_in[3];
  const float* b1 = (const float*)d_in[4];
  const float* W2 = (const float*)d_in[5];
  const float* b2 = (const float*)d_in[6];
  const float* W3 = (const float*)d_in[7];
  const float* b3 = (const float*)d_in[8];
  const float* g1 = (const float*)d_in[9];
  const float* be1 = (const float*)d_in[10];
  const float* m1 = (const float*)d_in[11];
  const float* v1 = (const float*)d_in[12];
  const float* g2 = (const float*)d_in[13];
  const float* be2 = (const float*)d_in[14];
  const float* m2 = (const float*)d_in[15];
  const float* v2 = (const float*)d_in[16];
  float* out = (float*)d_out;
  const int* src = ei;
  const int* dstp = ei + EE;

  int* wsi = (int*)d_ws;
  float* wsf = (float*)d_ws;
  int* off = wsi;
  int* cursor = wsi + OFF_CUR;
  int* bsum = wsi + OFF_BS;
  int* bpre = wsi + OFF_BP;
  int* csrc = wsi + OFF_CS;
  float* cew = wsf + OFF_CW;
  float* dis = wsf + OFF_DIS;
  float* s1 = wsf + OFF_AFF;
  float* u1 = s1 + 256;
  float* s2 = u1 + 256;
  float* u2 = s2 + 256;
  _Float16* hW = (_Float16*)(wsf + OFF_HW);
  _Float16* hb = (_Float16*)(wsi + OFF_HB);
  _Float16* wT1 = (_Float16*)(wsi + OFF_WT1);
  _Float16* wT2 = (_Float16*)(wsi + OFF_WT2);
  _Float16* wT3 = (_Float16*)(wsi + OFF_WT3);

  dim3 b256(256);
  const int EB = (EE + 255) / 256;
  // CSR build + norm precompute
  k_zero_off<<<NB, b256, 0, stream>>>(off);
  k_count<<<EB, b256, 0, stream>>>(src, dstp, off);
  k_scanA<<<NB, b256, 0, stream>>>(off, bsum);
  k_scanB<<<1, b256, 0, stream>>>(bsum, bpre, off);
  k_scanC<<<NB, b256, 0, stream>>>(off, bpre, cursor);
  k_fill<<<EB, b256, 0, stream>>>(src, dstp, ew, cursor, csrc, cew);
  k_degdis<<<NB, b256, 0, stream>>>(off, cew, dis);
  k_affine<<<1, b256, 0, stream>>>(g1, be1, m1, v1, g2, be2, m2, v2, s1, u1, s2, u2);
  // weight transpose+convert
  k_wt<<<dim3(3, 256), b256, 0, stream>>>(W1, wT1, 768, 256);
  k_wt<<<dim3(1, 256), b256, 0, stream>>>(W2, wT2, 256, 256);
  k_wt<<<dim3(1, 128), b256, 0, stream>>>(W3, wT3, 256, 128);

  const int GM = (NN + 63) / 64;  // 782
  const int AGB = (NN + 3) / 4;
  // Layer 1: x (fp32, inline-converted) @ W1
  k_gemm<1><<<dim3(2, GM), b256, 0, stream>>>(x, wT1, hW, NN, 768, 256);
  k_agg256<<<AGB, b256, 0, stream>>>(hW, dis, b1, off, csrc, cew, s1, u1, hb);
  // Layer 2: hb (fp16) @ W2
  k_gemm<0><<<dim3(2, GM), b256, 0, stream>>>(hb, wT2, hW, NN, 256, 256);
  k_agg256<<<AGB, b256, 0, stream>>>(hW, dis, b2, off, csrc, cew, s2, u2, hb);
  // Layer 3: hb @ W3, then aggregate + L2 norm -> d_out
  k_gemm<0><<<dim3(1, GM), b256, 0, stream>>>(hb, wT3, hW, NN, 256, 128);
  k_agg128_l2<<<AGB, b256, 0, stream>>>(hW, dis, b3, off, csrc, cew, out);
}